// Round 1
// baseline (159.498 us; speedup 1.0000x reference)
//
#include <hip/hip_runtime.h>

// 3-layer GCN on MI355X — R17: restructure k_gemm12 phase B.
// Prior best (R15): 148.4us, phase B = (2 nodes x 4 cols)/thread = 3 B LDS-read
// per FMA -> LDS-throughput-bound (~35us est vs 8.3us FMA floor).
// R17: (8 nodes x 4 cols)/thread with 4-way k-split inside each wave
// (kg = lane bits [4:5]); partials reduced by __shfl_xor(16)+__shfl_xor(32).
// h1 loads become 16-way same-address broadcasts (free); w loads amortized
// over 8 nodes -> effective LDS bytes/FMA < 1 B -> phase B ~VALU-bound.
// Structure otherwise identical:
//   memset(cursor) -> k_fill (cursor ends = in-degree)
//   -> k_gemm12 (agg1 + L1 + L2 linear -> t2s) -> k_agg2 -> k_agg3.
// gemm12: MB=16 (1250 blocks), W2 LDS-staged in 32-row chunks with REGISTER
// prefetch of chunk kc+1 during chunk-kc compute; float4 h1/w2 reads.
// agg2: 2 nodes/wave (half-wave x float4), 8 gathers in flight.
// Lessons (all measured): R3 multi-float atomic scatter=186us; R4 cooperative
// grid.sync~100us each; R7/R13 W2 streamed from global in k-loop =
// latency-bound (~51us) regardless of redundancy — W2 must be LDS-staged;
// R9/R11/R16 MB=32 always loses ~2-6us to MB=16 (625-block grid tail);
// R14 128t blocks = 2 waves can't hide chunk barriers (71us, VGPR 132);
// R10 wave-count bug (256t block = 4 waves); macro params must not be named
// 'w' (preprocessor substitutes into '.w' member tokens).

constexpr int NN  = 20000;  // nodes
constexpr int NE  = 320000; // edges
constexpr int F0  = 10;     // input feats
constexpr int F1  = 256;    // layer1 out
constexpr int F2  = 128;    // layer2 out
constexpr int MB  = 16;     // nodes per gemm12 tile
constexpr int CAP = 64;     // bucket capacity (max in-deg ~36, P(>=64)~2e-18)

// ---------- adjacency fill ----------

__global__ void k_fill(const int* __restrict__ src, const int* __restrict__ dst,
                       int* cursor, int* __restrict__ col) {
  int e = blockIdx.x * 256 + threadIdx.x;
  if (e >= NE) return;
  const int d = dst[e], s = src[e];
  const int pos = atomicAdd(&cursor[d], 1) & (CAP - 1);
  col[d * CAP + pos] = s;
}

// ---------- fused: a1 (LDS) -> h1 = relu(a1 W1 + b1) (LDS) -> t2s = dinv*(h1 W2)

__global__ __launch_bounds__(256) void k_gemm12(
    const float* __restrict__ x, const int* __restrict__ cursor,
    const int* __restrict__ col, const float* __restrict__ W1,
    const float* __restrict__ b1, const float* __restrict__ W2,
    float* __restrict__ t2s) {
  __shared__ float alds[MB * F0];     // 640 B
  __shared__ float h1[MB][F1 + 4];    // 16.6 KB, k-contiguous per node
  __shared__ float w2lds[32 * F2];    // 16 KB, one 32-row chunk of W2
  const int tid = threadIdx.x;
  const int n0 = blockIdx.x * MB;
  // stage 0: layer-1 aggregation into LDS; dinv on the fly from cursor
  {
    const int m = tid >> 4;
    const int f = tid & 15;
    if (f < F0) {
      const int n = n0 + m;
      const int deg = cursor[n];
      const int base = n * CAP;
      const float di = rsqrtf((float)(deg + 1));
      float acc = x[n * F0 + f] * di;  // self-loop
      int k = 0;
      for (; k + 3 < deg; k += 4) {
        const int s0 = col[base + k],     s1 = col[base + k + 1];
        const int s2 = col[base + k + 2], s3 = col[base + k + 3];
        const float d0 = rsqrtf((float)(cursor[s0] + 1));
        const float d1 = rsqrtf((float)(cursor[s1] + 1));
        const float d2 = rsqrtf((float)(cursor[s2] + 1));
        const float d3 = rsqrtf((float)(cursor[s3] + 1));
        acc += x[s0 * F0 + f] * d0 + x[s1 * F0 + f] * d1 +
               x[s2 * F0 + f] * d2 + x[s3 * F0 + f] * d3;
      }
      for (; k < deg; ++k) {
        const int s = col[base + k];
        acc += x[s * F0 + f] * rsqrtf((float)(cursor[s] + 1));
      }
      alds[m * F0 + f] = di * acc;
    }
  }
  // prefetch W2 chunk 0 while waiting at the barrier
  float4 pf0 = *((const float4*)W2 + tid);
  float4 pf1 = *((const float4*)W2 + tid + 256);
  float4 pf2 = *((const float4*)W2 + tid + 512);
  float4 pf3 = *((const float4*)W2 + tid + 768);
  __syncthreads();
  {  // phase A: thread = layer-1 channel c; h1[m][c] stride-1 in c
    const int c = tid;
    float w1r[F0];
#pragma unroll
    for (int k = 0; k < F0; ++k) w1r[k] = W1[k * F1 + c];
    const float bb = b1[c];
#pragma unroll
    for (int m = 0; m < MB; ++m) {
      float acc = bb;
#pragma unroll
      for (int k = 0; k < F0; ++k) acc += alds[m * F0 + k] * w1r[k];
      h1[m][c] = fmaxf(acc, 0.f);
    }
  }
  // phase B (R17): per-thread tile = 8 nodes x 4 cols, 4-way k-split in-wave.
  //   lane = kg*16 + ctl  (kg = k-split group, lane bits [4:5])
  //   wave = (nt, ctHigh): nt -> nodes nt*8..nt*8+7, ct = ctHigh*16 + ctl.
  // h1 reads: same addr across the 16 ctl lanes of a kg group -> broadcast.
  // w2 reads: 1 float4 per k, reused across 8 nodes.
  const int lane = tid & 63;
  const int wv   = tid >> 6;
  const int kg   = lane >> 4;        // 0..3 (k-split)
  const int ctl  = lane & 15;
  const int mBase = (wv >> 1) * 8;   // 0 or 8
  const int ct    = ((wv & 1) << 4) + ctl;  // 0..31 (float4 col group)
  float4 acc[8];
#pragma unroll
  for (int i = 0; i < 8; ++i) acc[i] = make_float4(0.f, 0.f, 0.f, 0.f);

  for (int kc = 0; kc < F1 / 32; ++kc) {
    __syncthreads();  // prev chunk consumed (kc=0: h1 written by phase A)
    {  // commit prefetched chunk to LDS
      float4* ldst = (float4*)w2lds;
      ldst[tid] = pf0;
      ldst[tid + 256] = pf1;
      ldst[tid + 512] = pf2;
      ldst[tid + 768] = pf3;
    }
    __syncthreads();
    if (kc + 1 < F1 / 32) {  // issue next-chunk loads; in flight during compute
      const float4* gnext = (const float4*)(W2 + (kc + 1) * 32 * F2);
      pf0 = gnext[tid];
      pf1 = gnext[tid + 256];
      pf2 = gnext[tid + 512];
      pf3 = gnext[tid + 768];
    }
#pragma unroll
    for (int kk = 0; kk < 8; kk += 4) {
      const int kl = (kg << 3) + kk;       // k within chunk (this thread's slice)
      const int kb = (kc << 5) + kl;       // k within h1 row
      const float4 w0v = *(const float4*)&w2lds[(kl + 0) * F2 + (ct << 2)];
      const float4 w1v = *(const float4*)&w2lds[(kl + 1) * F2 + (ct << 2)];
      const float4 w2v = *(const float4*)&w2lds[(kl + 2) * F2 + (ct << 2)];
      const float4 w3v = *(const float4*)&w2lds[(kl + 3) * F2 + (ct << 2)];
#pragma unroll
      for (int i = 0; i < 8; ++i) {
        const float4 hv = *(const float4*)&h1[mBase + i][kb];
        acc[i].x += hv.x * w0v.x + hv.y * w1v.x + hv.z * w2v.x + hv.w * w3v.x;
        acc[i].y += hv.x * w0v.y + hv.y * w1v.y + hv.z * w2v.y + hv.w * w3v.y;
        acc[i].z += hv.x * w0v.z + hv.y * w1v.z + hv.z * w2v.z + hv.w * w3v.z;
        acc[i].w += hv.x * w0v.w + hv.y * w1v.w + hv.z * w2v.w + hv.w * w3v.w;
      }
    }
  }
  // cross-kg reduce: kg lives in lane bits [4:5] -> butterfly over 16 and 32.
#pragma unroll
  for (int i = 0; i < 8; ++i) {
    acc[i].x += __shfl_xor(acc[i].x, 16);
    acc[i].y += __shfl_xor(acc[i].y, 16);
    acc[i].z += __shfl_xor(acc[i].z, 16);
    acc[i].w += __shfl_xor(acc[i].w, 16);
    acc[i].x += __shfl_xor(acc[i].x, 32);
    acc[i].y += __shfl_xor(acc[i].y, 32);
    acc[i].z += __shfl_xor(acc[i].z, 32);
    acc[i].w += __shfl_xor(acc[i].w, 32);
  }
  // every lane now holds all 8 sums; kg group g stores nodes mBase+2g, +2g+1.
  // static acc indices only (runtime-indexed arrays spill to scratch).
  float4 r0 = make_float4(0.f, 0.f, 0.f, 0.f), r1 = r0;
#pragma unroll
  for (int i = 0; i < 8; ++i) {
    if ((i >> 1) == kg) {
      if (i & 1) r1 = acc[i]; else r0 = acc[i];
    }
  }
  const int m = mBase + (kg << 1);
  const float d0 = rsqrtf((float)(cursor[n0 + m] + 1));
  const float d1 = rsqrtf((float)(cursor[n0 + m + 1] + 1));
  *(float4*)&t2s[(size_t)(n0 + m) * F2 + (ct << 2)] =
      make_float4(r0.x * d0, r0.y * d0, r0.z * d0, r0.w * d0);
  *(float4*)&t2s[(size_t)(n0 + m + 1) * F2 + (ct << 2)] =
      make_float4(r1.x * d1, r1.y * d1, r1.z * d1, r1.w * d1);
}

// ---------- layer-2 aggregation + layer-3 transform ----------
// 2 nodes per wave: half-wave (32 lanes) per node, float4 per lane (512B/row);
// 8 gathers in flight (deg~16 -> mostly 2 batches).

__global__ __launch_bounds__(256) void k_agg2(
    const float* __restrict__ t2s, const int* __restrict__ cursor,
    const int* __restrict__ col, const float* __restrict__ b2,
    const float* __restrict__ W3, float* __restrict__ t3s) {
  const int wave = (blockIdx.x * 256 + threadIdx.x) >> 6;
  const int lane = threadIdx.x & 63;
  const int half = lane >> 5;        // 0 or 1
  const int li   = lane & 31;
  const int n    = wave * 2 + half;  // 2500 blocks cover 20000 exactly
  if (n >= NN) return;
  const int deg = cursor[n];
  const int base = n * CAP;
  const int fx = li * 4;
  const float4 vs = *(const float4*)&t2s[(size_t)n * F2 + fx];
  float a0 = vs.x, a1 = vs.y, a2 = vs.z, a3 = vs.w;
  int k = 0;
  for (; k + 7 < deg; k += 8) {  // 8 coalesced 512B gathers in flight
    const int s0 = col[base + k],     s1 = col[base + k + 1];
    const int s2 = col[base + k + 2], s3 = col[base + k + 3];
    const int s4 = col[base + k + 4], s5 = col[base + k + 5];
    const int s6 = col[base + k + 6], s7 = col[base + k + 7];
    const float4 v0 = *(const float4*)&t2s[(size_t)s0 * F2 + fx];
    const float4 v1 = *(const float4*)&t2s[(size_t)s1 * F2 + fx];
    const float4 v2 = *(const float4*)&t2s[(size_t)s2 * F2 + fx];
    const float4 v3 = *(const float4*)&t2s[(size_t)s3 * F2 + fx];
    const float4 v4 = *(const float4*)&t2s[(size_t)s4 * F2 + fx];
    const float4 v5 = *(const float4*)&t2s[(size_t)s5 * F2 + fx];
    const float4 v6 = *(const float4*)&t2s[(size_t)s6 * F2 + fx];
    const float4 v7 = *(const float4*)&t2s[(size_t)s7 * F2 + fx];
    a0 += ((v0.x + v1.x) + (v2.x + v3.x)) + ((v4.x + v5.x) + (v6.x + v7.x));
    a1 += ((v0.y + v1.y) + (v2.y + v3.y)) + ((v4.y + v5.y) + (v6.y + v7.y));
    a2 += ((v0.z + v1.z) + (v2.z + v3.z)) + ((v4.z + v5.z) + (v6.z + v7.z));
    a3 += ((v0.w + v1.w) + (v2.w + v3.w)) + ((v4.w + v5.w) + (v6.w + v7.w));
  }
  for (; k + 3 < deg; k += 4) {
    const int s0 = col[base + k],     s1 = col[base + k + 1];
    const int s2 = col[base + k + 2], s3 = col[base + k + 3];
    const float4 v0 = *(const float4*)&t2s[(size_t)s0 * F2 + fx];
    const float4 v1 = *(const float4*)&t2s[(size_t)s1 * F2 + fx];
    const float4 v2 = *(const float4*)&t2s[(size_t)s2 * F2 + fx];
    const float4 v3 = *(const float4*)&t2s[(size_t)s3 * F2 + fx];
    a0 += (v0.x + v1.x) + (v2.x + v3.x);
    a1 += (v0.y + v1.y) + (v2.y + v3.y);
    a2 += (v0.z + v1.z) + (v2.z + v3.z);
    a3 += (v0.w + v1.w) + (v2.w + v3.w);
  }
  for (; k < deg; ++k) {
    const float4 v = *(const float4*)&t2s[(size_t)col[base + k] * F2 + fx];
    a0 += v.x; a1 += v.y; a2 += v.z; a3 += v.w;
  }
  const float di = rsqrtf((float)(deg + 1));
  const float4 bb = *(const float4*)&b2[fx];
  const float4 w3 = *(const float4*)&W3[fx];
  const float h0 = fmaxf(di * a0 + bb.x, 0.f);
  const float h1 = fmaxf(di * a1 + bb.y, 0.f);
  const float h2 = fmaxf(di * a2 + bb.z, 0.f);
  const float h3 = fmaxf(di * a3 + bb.w, 0.f);
  float p = (h0 * w3.x + h1 * w3.y) + (h2 * w3.z + h3 * w3.w);
#pragma unroll
  for (int off = 16; off > 0; off >>= 1) p += __shfl_down(p, off);  // within half
  if (li == 0) t3s[n] = di * p;
}

// ---------- layer-3 aggregation ----------

__global__ void k_agg3(const float* __restrict__ t3s, const int* __restrict__ cursor,
                       const int* __restrict__ col, const float* __restrict__ b3,
                       float* __restrict__ out) {
  int n = blockIdx.x * 256 + threadIdx.x;
  if (n >= NN) return;
  const int deg = cursor[n];
  const int base = n * CAP;
  float acc = t3s[n];
  int k = 0;
  for (; k + 7 < deg; k += 8)
    acc += ((t3s[col[base + k]] + t3s[col[base + k + 1]]) +
            (t3s[col[base + k + 2]] + t3s[col[base + k + 3]])) +
           ((t3s[col[base + k + 4]] + t3s[col[base + k + 5]]) +
            (t3s[col[base + k + 6]] + t3s[col[base + k + 7]]));
  for (; k < deg; ++k) acc += t3s[col[base + k]];
  out[n] = rsqrtf((float)(deg + 1)) * acc + b3[0];
}

extern "C" void kernel_launch(void* const* d_in, const int* in_sizes, int n_in,
                              void* d_out, int out_size, void* d_ws, size_t ws_size,
                              hipStream_t stream) {
  const float* x = (const float*)d_in[0];
  const int* ei = (const int*)d_in[1];
  const int* srcv = ei;       // edge_index[0]
  const int* dstv = ei + NE;  // edge_index[1]
  const float* W1 = (const float*)d_in[2];
  const float* b1 = (const float*)d_in[3];
  const float* W2 = (const float*)d_in[4];
  const float* b2 = (const float*)d_in[5];
  const float* W3 = (const float*)d_in[6];
  const float* b3 = (const float*)d_in[7];
  float* out = (float*)d_out;

  char* w = (char*)d_ws;
  auto alloc = [&](size_t bytes) -> void* {
    void* p = (void*)w;
    w += (bytes + 255) & ~(size_t)255;
    return p;
  };
  int*   cursor = (int*)  alloc(NN * 4);
  int*   col    = (int*)  alloc((size_t)NN * CAP * 4);
  float* t2s    = (float*)alloc((size_t)NN * F2 * 4);
  float* t3s    = (float*)alloc(NN * 4);

  (void)hipMemsetAsync(cursor, 0, NN * 4, stream);
  k_fill<<<(NE + 255) / 256, 256, 0, stream>>>(srcv, dstv, cursor, col);
  k_gemm12<<<NN / MB, 256, 0, stream>>>(x, cursor, col, W1, b1, W2, t2s);
  k_agg2<<<NN / 8, 256, 0, stream>>>(t2s, cursor, col, b2, W3, t3s);
  k_agg3<<<(NN + 255) / 256, 256, 0, stream>>>(t3s, cursor, col, b3, out);
}

// Round 2
// 147.560 us; speedup vs baseline: 1.0809x; 1.0809x over previous
//
#include <hip/hip_runtime.h>

// 3-layer GCN on MI355X — R18: R15 phase B restored + cooperative stage-0.
// R17 lesson (measured): k-split 8-node phase B halved LDS traffic but VGPR
// 128 -> occupancy 17%, gemm12 36->47us. Phase B is latency/occupancy-bound,
// NOT LDS-BW-bound. Keep the 2-node/4-col low-VGPR shape.
// R18 change: stage-0 split into 0a (cooperative edge staging: one col read +
// one cursor read per edge, stored as (src, rsqrt-weight) in LDS) and 0b
// (x-gathers with LDS-sourced addresses -> no dependent global chain, 10x
// less col/cursor traffic). W2 chunk-0 prefetch issued at kernel top so it is
// in flight under stage-0. LDS 39.3KB -> still 4 blocks/CU.
// Structure: memset(cursor) -> k_fill (cursor ends = in-degree)
//   -> k_gemm12 (agg1 + L1 + L2 linear -> t2s) -> k_agg2 -> k_agg3.
// gemm12: MB=16 (1250 blocks), W2 LDS-staged in 32-row chunks with REGISTER
// prefetch of chunk kc+1 during chunk-kc compute; float4 h1/w2 reads.
// agg2: 2 nodes/wave (half-wave x float4), 8 gathers in flight.
// Lessons (all measured): R3 multi-float atomic scatter=186us; R4 cooperative
// grid.sync~100us each; R7/R13 W2 streamed from global in k-loop =
// latency-bound (~51us) regardless of redundancy — W2 must be LDS-staged;
// R9/R11/R16 MB=32 always loses ~2-6us to MB=16 (625-block grid tail);
// R14 128t blocks = 2 waves can't hide chunk barriers (71us, VGPR 132);
// R10 wave-count bug (256t block = 4 waves); R17 8-node k-split = VGPR 128,
// -11us regression; macro params must not be named 'w'.

constexpr int NN  = 20000;  // nodes
constexpr int NE  = 320000; // edges
constexpr int F0  = 10;     // input feats
constexpr int F1  = 256;    // layer1 out
constexpr int F2  = 128;    // layer2 out
constexpr int MB  = 16;     // nodes per gemm12 tile
constexpr int CAP = 64;     // bucket capacity (max in-deg ~36, P(>=64)~2e-18)
constexpr int EMAX = 48;    // staged edges per node (max in-deg ~36)

// ---------- adjacency fill ----------

__global__ void k_fill(const int* __restrict__ src, const int* __restrict__ dst,
                       int* cursor, int* __restrict__ col) {
  int e = blockIdx.x * 256 + threadIdx.x;
  if (e >= NE) return;
  const int d = dst[e], s = src[e];
  const int pos = atomicAdd(&cursor[d], 1) & (CAP - 1);
  col[d * CAP + pos] = s;
}

// ---------- fused: a1 (LDS) -> h1 = relu(a1 W1 + b1) (LDS) -> t2s = dinv*(h1 W2)

__global__ __launch_bounds__(256) void k_gemm12(
    const float* __restrict__ x, const int* __restrict__ cursor,
    const int* __restrict__ col, const float* __restrict__ W1,
    const float* __restrict__ b1, const float* __restrict__ W2,
    float* __restrict__ t2s) {
  __shared__ float alds[MB * F0];     // 640 B
  __shared__ float h1[MB][F1 + 4];    // 16.6 KB, k-contiguous per node
  __shared__ float w2lds[32 * F2];    // 16 KB, one 32-row chunk of W2
  __shared__ int   es[MB][EMAX];      // 3 KB, staged edge sources
  __shared__ float ew[MB][EMAX];      // 3 KB, staged edge weights
  const int tid = threadIdx.x;
  const int n0 = blockIdx.x * MB;
  // W2 chunk-0 prefetch FIRST: in flight under all of stage 0
  float4 pf0 = *((const float4*)W2 + tid);
  float4 pf1 = *((const float4*)W2 + tid + 256);
  float4 pf2 = *((const float4*)W2 + tid + 512);
  float4 pf3 = *((const float4*)W2 + tid + 768);
  // stage 0a: cooperative edge staging — 16 threads per node, one edge each.
  // One col read + one cursor gather per edge (was 10x redundant + dependent).
  {
    const int m = tid >> 4;
    const int j0 = tid & 15;
    const int n = n0 + m;
    const int deg = min(cursor[n], EMAX);
    const int base = n * CAP;
    for (int j = j0; j < deg; j += 16) {
      const int s = col[base + j];
      es[m][j] = s;
      ew[m][j] = rsqrtf((float)(cursor[s] + 1));
    }
  }
  __syncthreads();
  // stage 0b: x-gathers with LDS-sourced addresses (independent, pipelined)
  {
    const int m = tid >> 4;
    const int f = tid & 15;
    if (f < F0) {
      const int n = n0 + m;
      const int deg = min(cursor[n], EMAX);
      const float di = rsqrtf((float)(cursor[n] + 1));
      float acc = x[n * F0 + f] * di;  // self-loop
      int j = 0;
      for (; j + 3 < deg; j += 4) {
        const int s0 = es[m][j],     s1 = es[m][j + 1];
        const int s2 = es[m][j + 2], s3 = es[m][j + 3];
        const float q0 = ew[m][j],     q1 = ew[m][j + 1];
        const float q2 = ew[m][j + 2], q3 = ew[m][j + 3];
        acc += x[s0 * F0 + f] * q0 + x[s1 * F0 + f] * q1 +
               x[s2 * F0 + f] * q2 + x[s3 * F0 + f] * q3;
      }
      for (; j < deg; ++j) acc += x[es[m][j] * F0 + f] * ew[m][j];
      alds[m * F0 + f] = di * acc;
    }
  }
  __syncthreads();
  {  // phase A: thread = layer-1 channel c; h1[m][c] stride-1 in c
    const int c = tid;
    float w1r[F0];
#pragma unroll
    for (int k = 0; k < F0; ++k) w1r[k] = W1[k * F1 + c];
    const float bb = b1[c];
#pragma unroll
    for (int m = 0; m < MB; ++m) {
      float acc = bb;
#pragma unroll
      for (int k = 0; k < F0; ++k) acc += alds[m * F0 + k] * w1r[k];
      h1[m][c] = fmaxf(acc, 0.f);
    }
  }
  // phase B: 2 nodes x 4 cols per thread; W2 LDS-staged in 32-row chunks
  // with REGISTER PREFETCH of chunk kc+1 during chunk-kc compute. (R15 exact)
  const int cg_ = tid & 31;
  const int m0 = (tid >> 5) * 2;
  float a00 = 0.f, a01 = 0.f, a02 = 0.f, a03 = 0.f;
  float a10 = 0.f, a11 = 0.f, a12 = 0.f, a13 = 0.f;
#define FMA4(av, bv, vw)                                            \
  a00 += (av) * (vw).x; a01 += (av) * (vw).y;                       \
  a02 += (av) * (vw).z; a03 += (av) * (vw).w;                       \
  a10 += (bv) * (vw).x; a11 += (bv) * (vw).y;                       \
  a12 += (bv) * (vw).z; a13 += (bv) * (vw).w;
  for (int kc = 0; kc < F1 / 32; ++kc) {
    __syncthreads();  // prev chunk consumed (kc=0: h1 written by phase A)
    {  // commit prefetched chunk to LDS
      float4* ldst = (float4*)w2lds;
      ldst[tid] = pf0;
      ldst[tid + 256] = pf1;
      ldst[tid + 512] = pf2;
      ldst[tid + 768] = pf3;
    }
    __syncthreads();
    if (kc + 1 < F1 / 32) {  // issue next-chunk loads; in flight during compute
      const float4* gnext = (const float4*)(W2 + (kc + 1) * 32 * F2);
      pf0 = gnext[tid];
      pf1 = gnext[tid + 256];
      pf2 = gnext[tid + 512];
      pf3 = gnext[tid + 768];
    }
#pragma unroll
    for (int kk = 0; kk < 32; kk += 4) {
      const int k = kc * 32 + kk;
      const float4 ha = *(const float4*)&h1[m0][k];
      const float4 hb = *(const float4*)&h1[m0 + 1][k];
      const float4 w0 = *(const float4*)&w2lds[(kk + 0) * F2 + cg_ * 4];
      const float4 w1v = *(const float4*)&w2lds[(kk + 1) * F2 + cg_ * 4];
      const float4 w2v = *(const float4*)&w2lds[(kk + 2) * F2 + cg_ * 4];
      const float4 w3v = *(const float4*)&w2lds[(kk + 3) * F2 + cg_ * 4];
      FMA4(ha.x, hb.x, w0);
      FMA4(ha.y, hb.y, w1v);
      FMA4(ha.z, hb.z, w2v);
      FMA4(ha.w, hb.w, w3v);
    }
  }
#undef FMA4
  const float d0 = rsqrtf((float)(cursor[n0 + m0] + 1));
  const float d1 = rsqrtf((float)(cursor[n0 + m0 + 1] + 1));
  *(float4*)&t2s[(size_t)(n0 + m0) * F2 + cg_ * 4] =
      make_float4(a00 * d0, a01 * d0, a02 * d0, a03 * d0);
  *(float4*)&t2s[(size_t)(n0 + m0 + 1) * F2 + cg_ * 4] =
      make_float4(a10 * d1, a11 * d1, a12 * d1, a13 * d1);
}

// ---------- layer-2 aggregation + layer-3 transform ----------
// 2 nodes per wave: half-wave (32 lanes) per node, float4 per lane (512B/row);
// 8 gathers in flight (deg~16 -> mostly 2 batches).

__global__ __launch_bounds__(256) void k_agg2(
    const float* __restrict__ t2s, const int* __restrict__ cursor,
    const int* __restrict__ col, const float* __restrict__ b2,
    const float* __restrict__ W3, float* __restrict__ t3s) {
  const int wave = (blockIdx.x * 256 + threadIdx.x) >> 6;
  const int lane = threadIdx.x & 63;
  const int half = lane >> 5;        // 0 or 1
  const int li   = lane & 31;
  const int n    = wave * 2 + half;  // 2500 blocks cover 20000 exactly
  if (n >= NN) return;
  const int deg = cursor[n];
  const int base = n * CAP;
  const int fx = li * 4;
  const float4 vs = *(const float4*)&t2s[(size_t)n * F2 + fx];
  float a0 = vs.x, a1 = vs.y, a2 = vs.z, a3 = vs.w;
  int k = 0;
  for (; k + 7 < deg; k += 8) {  // 8 coalesced 512B gathers in flight
    const int s0 = col[base + k],     s1 = col[base + k + 1];
    const int s2 = col[base + k + 2], s3 = col[base + k + 3];
    const int s4 = col[base + k + 4], s5 = col[base + k + 5];
    const int s6 = col[base + k + 6], s7 = col[base + k + 7];
    const float4 v0 = *(const float4*)&t2s[(size_t)s0 * F2 + fx];
    const float4 v1 = *(const float4*)&t2s[(size_t)s1 * F2 + fx];
    const float4 v2 = *(const float4*)&t2s[(size_t)s2 * F2 + fx];
    const float4 v3 = *(const float4*)&t2s[(size_t)s3 * F2 + fx];
    const float4 v4 = *(const float4*)&t2s[(size_t)s4 * F2 + fx];
    const float4 v5 = *(const float4*)&t2s[(size_t)s5 * F2 + fx];
    const float4 v6 = *(const float4*)&t2s[(size_t)s6 * F2 + fx];
    const float4 v7 = *(const float4*)&t2s[(size_t)s7 * F2 + fx];
    a0 += ((v0.x + v1.x) + (v2.x + v3.x)) + ((v4.x + v5.x) + (v6.x + v7.x));
    a1 += ((v0.y + v1.y) + (v2.y + v3.y)) + ((v4.y + v5.y) + (v6.y + v7.y));
    a2 += ((v0.z + v1.z) + (v2.z + v3.z)) + ((v4.z + v5.z) + (v6.z + v7.z));
    a3 += ((v0.w + v1.w) + (v2.w + v3.w)) + ((v4.w + v5.w) + (v6.w + v7.w));
  }
  for (; k + 3 < deg; k += 4) {
    const int s0 = col[base + k],     s1 = col[base + k + 1];
    const int s2 = col[base + k + 2], s3 = col[base + k + 3];
    const float4 v0 = *(const float4*)&t2s[(size_t)s0 * F2 + fx];
    const float4 v1 = *(const float4*)&t2s[(size_t)s1 * F2 + fx];
    const float4 v2 = *(const float4*)&t2s[(size_t)s2 * F2 + fx];
    const float4 v3 = *(const float4*)&t2s[(size_t)s3 * F2 + fx];
    a0 += (v0.x + v1.x) + (v2.x + v3.x);
    a1 += (v0.y + v1.y) + (v2.y + v3.y);
    a2 += (v0.z + v1.z) + (v2.z + v3.z);
    a3 += (v0.w + v1.w) + (v2.w + v3.w);
  }
  for (; k < deg; ++k) {
    const float4 v = *(const float4*)&t2s[(size_t)col[base + k] * F2 + fx];
    a0 += v.x; a1 += v.y; a2 += v.z; a3 += v.w;
  }
  const float di = rsqrtf((float)(deg + 1));
  const float4 bb = *(const float4*)&b2[fx];
  const float4 w3 = *(const float4*)&W3[fx];
  const float h0 = fmaxf(di * a0 + bb.x, 0.f);
  const float h1 = fmaxf(di * a1 + bb.y, 0.f);
  const float h2 = fmaxf(di * a2 + bb.z, 0.f);
  const float h3 = fmaxf(di * a3 + bb.w, 0.f);
  float p = (h0 * w3.x + h1 * w3.y) + (h2 * w3.z + h3 * w3.w);
#pragma unroll
  for (int off = 16; off > 0; off >>= 1) p += __shfl_down(p, off);  // within half
  if (li == 0) t3s[n] = di * p;
}

// ---------- layer-3 aggregation ----------

__global__ void k_agg3(const float* __restrict__ t3s, const int* __restrict__ cursor,
                       const int* __restrict__ col, const float* __restrict__ b3,
                       float* __restrict__ out) {
  int n = blockIdx.x * 256 + threadIdx.x;
  if (n >= NN) return;
  const int deg = cursor[n];
  const int base = n * CAP;
  float acc = t3s[n];
  int k = 0;
  for (; k + 7 < deg; k += 8)
    acc += ((t3s[col[base + k]] + t3s[col[base + k + 1]]) +
            (t3s[col[base + k + 2]] + t3s[col[base + k + 3]])) +
           ((t3s[col[base + k + 4]] + t3s[col[base + k + 5]]) +
            (t3s[col[base + k + 6]] + t3s[col[base + k + 7]]));
  for (; k < deg; ++k) acc += t3s[col[base + k]];
  out[n] = rsqrtf((float)(deg + 1)) * acc + b3[0];
}

extern "C" void kernel_launch(void* const* d_in, const int* in_sizes, int n_in,
                              void* d_out, int out_size, void* d_ws, size_t ws_size,
                              hipStream_t stream) {
  const float* x = (const float*)d_in[0];
  const int* ei = (const int*)d_in[1];
  const int* srcv = ei;       // edge_index[0]
  const int* dstv = ei + NE;  // edge_index[1]
  const float* W1 = (const float*)d_in[2];
  const float* b1 = (const float*)d_in[3];
  const float* W2 = (const float*)d_in[4];
  const float* b2 = (const float*)d_in[5];
  const float* W3 = (const float*)d_in[6];
  const float* b3 = (const float*)d_in[7];
  float* out = (float*)d_out;

  char* w = (char*)d_ws;
  auto alloc = [&](size_t bytes) -> void* {
    void* p = (void*)w;
    w += (bytes + 255) & ~(size_t)255;
    return p;
  };
  int*   cursor = (int*)  alloc(NN * 4);
  int*   col    = (int*)  alloc((size_t)NN * CAP * 4);
  float* t2s    = (float*)alloc((size_t)NN * F2 * 4);
  float* t3s    = (float*)alloc(NN * 4);

  (void)hipMemsetAsync(cursor, 0, NN * 4, stream);
  k_fill<<<(NE + 255) / 256, 256, 0, stream>>>(srcv, dstv, cursor, col);
  k_gemm12<<<NN / MB, 256, 0, stream>>>(x, cursor, col, W1, b1, W2, t2s);
  k_agg2<<<NN / 8, 256, 0, stream>>>(t2s, cursor, col, b2, W3, t3s);
  k_agg3<<<(NN + 255) / 256, 256, 0, stream>>>(t3s, cursor, col, b3, out);
}

// Round 3
// 137.694 us; speedup vs baseline: 1.1584x; 1.0717x over previous
//
#include <hip/hip_runtime.h>
#include <hip/hip_fp16.h>

// 3-layer GCN on MI355X — R19: fp16 t2s + 16-lane-per-node agg3.
// Bookkeeping (measured R0-R2): gemm12 ~35us; non-gemm12 remainder ~112us
// (fill + agg2 + agg3 + memset + gaps). agg2 gathers 320k x 512B = 164MB of
// random t2s rows -> dominant remainder term. R19: t2s stored as fp16
// (halves gather volume to 82MB; final-output error ~1e-5, values O(0.05-1));
// agg3 restructured to 4 nodes/wave, 16 lanes/node: col reads coalesce to
// 64B bursts (was 64 lines/wave-load), shfl_xor 8/4/2/1 reduce.
// gemm12/fill/agg2 structure otherwise R18-exact.
// Structure: memset(cursor) -> k_fill (cursor ends = in-degree)
//   -> k_gemm12 (agg1 + L1 + L2 linear -> t2h fp16) -> k_agg2 -> k_agg3.
// Lessons (all measured): R3 multi-float atomic scatter=186us; R4 cooperative
// grid.sync~100us each; R7/R13 W2 streamed from global in k-loop =
// latency-bound (~51us) regardless of redundancy — W2 must be LDS-staged;
// R9/R11/R16 MB=32 always loses ~2-6us to MB=16 (625-block grid tail);
// R14 128t blocks = 2 waves can't hide chunk barriers (71us, VGPR 132);
// R10 wave-count bug (256t block = 4 waves); R17 8-node k-split phase B =
// VGPR 128, occupancy 17%, -11us (phase B must stay low-VGPR);
// R18 coop stage-0 = +0.8us only; macro params must not be named 'w'.

constexpr int NN  = 20000;  // nodes
constexpr int NE  = 320000; // edges
constexpr int F0  = 10;     // input feats
constexpr int F1  = 256;    // layer1 out
constexpr int F2  = 128;    // layer2 out
constexpr int MB  = 16;     // nodes per gemm12 tile
constexpr int CAP = 64;     // bucket capacity (max in-deg ~36, P(>=64)~2e-18)
constexpr int EMAX = 48;    // staged edges per node (max in-deg ~36)

// ---------- adjacency fill ----------

__global__ void k_fill(const int* __restrict__ src, const int* __restrict__ dst,
                       int* cursor, int* __restrict__ col) {
  int e = blockIdx.x * 256 + threadIdx.x;
  if (e >= NE) return;
  const int d = dst[e], s = src[e];
  const int pos = atomicAdd(&cursor[d], 1) & (CAP - 1);
  col[d * CAP + pos] = s;
}

// ---------- fused: a1 (LDS) -> h1 = relu(a1 W1 + b1) (LDS) -> t2h = fp16(dinv*(h1 W2))

__global__ __launch_bounds__(256) void k_gemm12(
    const float* __restrict__ x, const int* __restrict__ cursor,
    const int* __restrict__ col, const float* __restrict__ W1,
    const float* __restrict__ b1, const float* __restrict__ W2,
    __half* __restrict__ t2h) {
  __shared__ float alds[MB * F0];     // 640 B
  __shared__ float h1[MB][F1 + 4];    // 16.6 KB, k-contiguous per node
  __shared__ float w2lds[32 * F2];    // 16 KB, one 32-row chunk of W2
  __shared__ int   es[MB][EMAX];      // 3 KB, staged edge sources
  __shared__ float ew[MB][EMAX];      // 3 KB, staged edge weights
  const int tid = threadIdx.x;
  const int n0 = blockIdx.x * MB;
  // W2 chunk-0 prefetch FIRST: in flight under all of stage 0
  float4 pf0 = *((const float4*)W2 + tid);
  float4 pf1 = *((const float4*)W2 + tid + 256);
  float4 pf2 = *((const float4*)W2 + tid + 512);
  float4 pf3 = *((const float4*)W2 + tid + 768);
  // stage 0a: cooperative edge staging — 16 threads per node, one edge each.
  {
    const int m = tid >> 4;
    const int j0 = tid & 15;
    const int n = n0 + m;
    const int deg = min(cursor[n], EMAX);
    const int base = n * CAP;
    for (int j = j0; j < deg; j += 16) {
      const int s = col[base + j];
      es[m][j] = s;
      ew[m][j] = rsqrtf((float)(cursor[s] + 1));
    }
  }
  __syncthreads();
  // stage 0b: x-gathers with LDS-sourced addresses (independent, pipelined)
  {
    const int m = tid >> 4;
    const int f = tid & 15;
    if (f < F0) {
      const int n = n0 + m;
      const int deg = min(cursor[n], EMAX);
      const float di = rsqrtf((float)(cursor[n] + 1));
      float acc = x[n * F0 + f] * di;  // self-loop
      int j = 0;
      for (; j + 3 < deg; j += 4) {
        const int s0 = es[m][j],     s1 = es[m][j + 1];
        const int s2 = es[m][j + 2], s3 = es[m][j + 3];
        const float q0 = ew[m][j],     q1 = ew[m][j + 1];
        const float q2 = ew[m][j + 2], q3 = ew[m][j + 3];
        acc += x[s0 * F0 + f] * q0 + x[s1 * F0 + f] * q1 +
               x[s2 * F0 + f] * q2 + x[s3 * F0 + f] * q3;
      }
      for (; j < deg; ++j) acc += x[es[m][j] * F0 + f] * ew[m][j];
      alds[m * F0 + f] = di * acc;
    }
  }
  __syncthreads();
  {  // phase A: thread = layer-1 channel c; h1[m][c] stride-1 in c
    const int c = tid;
    float w1r[F0];
#pragma unroll
    for (int k = 0; k < F0; ++k) w1r[k] = W1[k * F1 + c];
    const float bb = b1[c];
#pragma unroll
    for (int m = 0; m < MB; ++m) {
      float acc = bb;
#pragma unroll
      for (int k = 0; k < F0; ++k) acc += alds[m * F0 + k] * w1r[k];
      h1[m][c] = fmaxf(acc, 0.f);
    }
  }
  // phase B: 2 nodes x 4 cols per thread; W2 LDS-staged in 32-row chunks
  // with REGISTER PREFETCH of chunk kc+1 during chunk-kc compute. (R15 exact)
  const int cg_ = tid & 31;
  const int m0 = (tid >> 5) * 2;
  float a00 = 0.f, a01 = 0.f, a02 = 0.f, a03 = 0.f;
  float a10 = 0.f, a11 = 0.f, a12 = 0.f, a13 = 0.f;
#define FMA4(av, bv, vw)                                            \
  a00 += (av) * (vw).x; a01 += (av) * (vw).y;                       \
  a02 += (av) * (vw).z; a03 += (av) * (vw).w;                       \
  a10 += (bv) * (vw).x; a11 += (bv) * (vw).y;                       \
  a12 += (bv) * (vw).z; a13 += (bv) * (vw).w;
  for (int kc = 0; kc < F1 / 32; ++kc) {
    __syncthreads();  // prev chunk consumed (kc=0: h1 written by phase A)
    {  // commit prefetched chunk to LDS
      float4* ldst = (float4*)w2lds;
      ldst[tid] = pf0;
      ldst[tid + 256] = pf1;
      ldst[tid + 512] = pf2;
      ldst[tid + 768] = pf3;
    }
    __syncthreads();
    if (kc + 1 < F1 / 32) {  // issue next-chunk loads; in flight during compute
      const float4* gnext = (const float4*)(W2 + (kc + 1) * 32 * F2);
      pf0 = gnext[tid];
      pf1 = gnext[tid + 256];
      pf2 = gnext[tid + 512];
      pf3 = gnext[tid + 768];
    }
#pragma unroll
    for (int kk = 0; kk < 32; kk += 4) {
      const int k = kc * 32 + kk;
      const float4 ha = *(const float4*)&h1[m0][k];
      const float4 hb = *(const float4*)&h1[m0 + 1][k];
      const float4 w0 = *(const float4*)&w2lds[(kk + 0) * F2 + cg_ * 4];
      const float4 w1v = *(const float4*)&w2lds[(kk + 1) * F2 + cg_ * 4];
      const float4 w2v = *(const float4*)&w2lds[(kk + 2) * F2 + cg_ * 4];
      const float4 w3v = *(const float4*)&w2lds[(kk + 3) * F2 + cg_ * 4];
      FMA4(ha.x, hb.x, w0);
      FMA4(ha.y, hb.y, w1v);
      FMA4(ha.z, hb.z, w2v);
      FMA4(ha.w, hb.w, w3v);
    }
  }
#undef FMA4
  const float d0 = rsqrtf((float)(cursor[n0 + m0] + 1));
  const float d1 = rsqrtf((float)(cursor[n0 + m0 + 1] + 1));
  union PK { uint2 u; __half2 h[2]; };
  PK p0; p0.h[0] = __floats2half2_rn(a00 * d0, a01 * d0);
         p0.h[1] = __floats2half2_rn(a02 * d0, a03 * d0);
  PK p1; p1.h[0] = __floats2half2_rn(a10 * d1, a11 * d1);
         p1.h[1] = __floats2half2_rn(a12 * d1, a13 * d1);
  *(uint2*)&t2h[(size_t)(n0 + m0) * F2 + cg_ * 4] = p0.u;
  *(uint2*)&t2h[(size_t)(n0 + m0 + 1) * F2 + cg_ * 4] = p1.u;
}

// ---------- layer-2 aggregation + layer-3 transform ----------
// 2 nodes per wave: half-wave (32 lanes) per node, 8 B/lane (4 fp16);
// 8 gathers in flight (deg~16 -> mostly 2 batches). fp16 rows = 256 B.

__device__ inline void acc_h4(uint2 u, float& a0, float& a1, float& a2, float& a3) {
  union { uint2 u; __half2 h[2]; } pk;
  pk.u = u;
  const float2 f0 = __half22float2(pk.h[0]);
  const float2 f1 = __half22float2(pk.h[1]);
  a0 += f0.x; a1 += f0.y; a2 += f1.x; a3 += f1.y;
}

__global__ __launch_bounds__(256) void k_agg2(
    const __half* __restrict__ t2h, const int* __restrict__ cursor,
    const int* __restrict__ col, const float* __restrict__ b2,
    const float* __restrict__ W3, float* __restrict__ t3s) {
  const int wave = (blockIdx.x * 256 + threadIdx.x) >> 6;
  const int lane = threadIdx.x & 63;
  const int half = lane >> 5;        // 0 or 1
  const int li   = lane & 31;
  const int n    = wave * 2 + half;  // 2500 blocks cover 20000 exactly
  if (n >= NN) return;
  const int deg = cursor[n];
  const int base = n * CAP;
  const int fx = li * 4;
  float a0 = 0.f, a1 = 0.f, a2 = 0.f, a3 = 0.f;
  acc_h4(*(const uint2*)&t2h[(size_t)n * F2 + fx], a0, a1, a2, a3);  // self
  int k = 0;
  for (; k + 7 < deg; k += 8) {  // 8 coalesced 256B gathers in flight
    const int s0 = col[base + k],     s1 = col[base + k + 1];
    const int s2 = col[base + k + 2], s3 = col[base + k + 3];
    const int s4 = col[base + k + 4], s5 = col[base + k + 5];
    const int s6 = col[base + k + 6], s7 = col[base + k + 7];
    const uint2 v0 = *(const uint2*)&t2h[(size_t)s0 * F2 + fx];
    const uint2 v1 = *(const uint2*)&t2h[(size_t)s1 * F2 + fx];
    const uint2 v2 = *(const uint2*)&t2h[(size_t)s2 * F2 + fx];
    const uint2 v3 = *(const uint2*)&t2h[(size_t)s3 * F2 + fx];
    const uint2 v4 = *(const uint2*)&t2h[(size_t)s4 * F2 + fx];
    const uint2 v5 = *(const uint2*)&t2h[(size_t)s5 * F2 + fx];
    const uint2 v6 = *(const uint2*)&t2h[(size_t)s6 * F2 + fx];
    const uint2 v7 = *(const uint2*)&t2h[(size_t)s7 * F2 + fx];
    acc_h4(v0, a0, a1, a2, a3); acc_h4(v1, a0, a1, a2, a3);
    acc_h4(v2, a0, a1, a2, a3); acc_h4(v3, a0, a1, a2, a3);
    acc_h4(v4, a0, a1, a2, a3); acc_h4(v5, a0, a1, a2, a3);
    acc_h4(v6, a0, a1, a2, a3); acc_h4(v7, a0, a1, a2, a3);
  }
  for (; k + 3 < deg; k += 4) {
    const int s0 = col[base + k],     s1 = col[base + k + 1];
    const int s2 = col[base + k + 2], s3 = col[base + k + 3];
    const uint2 v0 = *(const uint2*)&t2h[(size_t)s0 * F2 + fx];
    const uint2 v1 = *(const uint2*)&t2h[(size_t)s1 * F2 + fx];
    const uint2 v2 = *(const uint2*)&t2h[(size_t)s2 * F2 + fx];
    const uint2 v3 = *(const uint2*)&t2h[(size_t)s3 * F2 + fx];
    acc_h4(v0, a0, a1, a2, a3); acc_h4(v1, a0, a1, a2, a3);
    acc_h4(v2, a0, a1, a2, a3); acc_h4(v3, a0, a1, a2, a3);
  }
  for (; k < deg; ++k) {
    acc_h4(*(const uint2*)&t2h[(size_t)col[base + k] * F2 + fx], a0, a1, a2, a3);
  }
  const float di = rsqrtf((float)(deg + 1));
  const float4 bb = *(const float4*)&b2[fx];
  const float4 w3 = *(const float4*)&W3[fx];
  const float h0 = fmaxf(di * a0 + bb.x, 0.f);
  const float h1 = fmaxf(di * a1 + bb.y, 0.f);
  const float h2 = fmaxf(di * a2 + bb.z, 0.f);
  const float h3 = fmaxf(di * a3 + bb.w, 0.f);
  float p = (h0 * w3.x + h1 * w3.y) + (h2 * w3.z + h3 * w3.w);
#pragma unroll
  for (int off = 16; off > 0; off >>= 1) p += __shfl_down(p, off);  // within half
  if (li == 0) t3s[n] = di * p;
}

// ---------- layer-3 aggregation ----------
// R19: 4 nodes per wave, 16 lanes per node -> col reads coalesce to 64B
// bursts; per-edge t3s gathers run 16-wide; shfl_xor 8/4/2/1 reduce.

__global__ __launch_bounds__(256) void k_agg3(
    const float* __restrict__ t3s, const int* __restrict__ cursor,
    const int* __restrict__ col, const float* __restrict__ b3,
    float* __restrict__ out) {
  const int wave = (blockIdx.x * 256 + threadIdx.x) >> 6;
  const int lane = threadIdx.x & 63;
  const int sub  = lane >> 4;       // 0..3
  const int li   = lane & 15;
  const int n    = wave * 4 + sub;  // 1250 blocks x 16 nodes cover 20000 exactly
  if (n >= NN) return;
  const int deg = cursor[n];
  const int base = n * CAP;
  float acc = 0.f;
  for (int j = li; j < deg; j += 16) acc += t3s[col[base + j]];
  acc += __shfl_xor(acc, 8);
  acc += __shfl_xor(acc, 4);
  acc += __shfl_xor(acc, 2);
  acc += __shfl_xor(acc, 1);
  if (li == 0)
    out[n] = rsqrtf((float)(deg + 1)) * (acc + t3s[n]) + b3[0];
}

extern "C" void kernel_launch(void* const* d_in, const int* in_sizes, int n_in,
                              void* d_out, int out_size, void* d_ws, size_t ws_size,
                              hipStream_t stream) {
  const float* x = (const float*)d_in[0];
  const int* ei = (const int*)d_in[1];
  const int* srcv = ei;       // edge_index[0]
  const int* dstv = ei + NE;  // edge_index[1]
  const float* W1 = (const float*)d_in[2];
  const float* b1 = (const float*)d_in[3];
  const float* W2 = (const float*)d_in[4];
  const float* b2 = (const float*)d_in[5];
  const float* W3 = (const float*)d_in[6];
  const float* b3 = (const float*)d_in[7];
  float* out = (float*)d_out;

  char* w = (char*)d_ws;
  auto alloc = [&](size_t bytes) -> void* {
    void* p = (void*)w;
    w += (bytes + 255) & ~(size_t)255;
    return p;
  };
  int*    cursor = (int*)   alloc(NN * 4);
  int*    col    = (int*)   alloc((size_t)NN * CAP * 4);
  __half* t2h    = (__half*)alloc((size_t)NN * F2 * 2);
  float*  t3s    = (float*) alloc(NN * 4);

  (void)hipMemsetAsync(cursor, 0, NN * 4, stream);
  k_fill<<<(NE + 255) / 256, 256, 0, stream>>>(srcv, dstv, cursor, col);
  k_gemm12<<<NN / MB, 256, 0, stream>>>(x, cursor, col, W1, b1, W2, t2h);
  k_agg2<<<NN / 8, 256, 0, stream>>>(t2h, cursor, col, b2, W3, t3s);
  k_agg3<<<(NN + 15) / 16, 256, 0, stream>>>(t3s, cursor, col, b3, out);
}

// Round 4
// 124.424 us; speedup vs baseline: 1.2819x; 1.1066x over previous
//
#include <hip/hip_runtime.h>
#include <hip/hip_fp16.h>

// 3-layer GCN on MI355X — R20: MFMA fp16 phase B in k_gemm12.
// Budget (measured R0-R3): ~45.5us workspace re-poison (fixed, in window),
// gemm12 ~35us, remainder ~57us. gemm12 phase B = 1.31 GFLOP fp32-VALU GEMM
// (floor 8.3us @157TF, achieved ~25us). R20 moves it to f16 MFMA
// (16x16x32_f16, fp32 accum): new k_w2t pre-transposes W2 -> W2t[n][k] fp16
// (B^T fragment layout, halves staging traffic); phase A writes h1 fp16
// [16][264]; per wave 2 tiles x K=256 in 4 chunks of 64 w/ reg-prefetch.
// Precision calibrated by R19: fp16 t2s gave absmax 1.2e-4 PASS; fp16 MFMA
// inputs add same-order error -> expect ~3-6e-4.
// Fragment layouts (m89/m97-verified): A/B: row(m)|col(n) = lane&15,
// k = (lane>>4)*8 + i (b128 per lane); C/D: col = lane&15,
// row = (lane>>4)*4 + reg.
// Structure: memset(cursor) -> k_fill -> k_w2t -> k_gemm12 -> k_agg2 -> k_agg3.
// Lessons (all measured): R3 multi-float atomic scatter=186us; R4 cooperative
// grid.sync~100us each; R7/R13 W2 streamed from global in k-loop =
// latency-bound — W2 must be LDS-staged; R9/R11/R16 MB=32 loses 2-6us;
// R14 128t blocks can't hide chunk barriers; R17 8-node k-split phase B =
// VGPR 128, occupancy 17%, -11us (phase B must stay low-VGPR); R18 coop
// stage-0 = +0.8us; R19 fp16 t2s + 16-lane agg3 = -9.9us, absmax 1.2e-4 OK.

constexpr int NN  = 20000;  // nodes
constexpr int NE  = 320000; // edges
constexpr int F0  = 10;     // input feats
constexpr int F1  = 256;    // layer1 out
constexpr int F2  = 128;    // layer2 out
constexpr int MB  = 16;     // nodes per gemm12 tile (= MFMA M)
constexpr int CAP = 64;     // bucket capacity (max in-deg ~36)
constexpr int EMAX = 48;    // staged edges per node

typedef _Float16 f16x8 __attribute__((ext_vector_type(8)));
typedef float    f32x4 __attribute__((ext_vector_type(4)));

constexpr int H1S = 264;    // h1h row stride (f16): mult of 8, 528B rows
constexpr int BKC = 64;     // K per staged chunk
constexpr int W2S = 72;     // w2t_lds row stride (f16): mult of 8, 144B rows

// ---------- adjacency fill ----------

__global__ void k_fill(const int* __restrict__ src, const int* __restrict__ dst,
                       int* cursor, int* __restrict__ col) {
  int e = blockIdx.x * 256 + threadIdx.x;
  if (e >= NE) return;
  const int d = dst[e], s = src[e];
  const int pos = atomicAdd(&cursor[d], 1) & (CAP - 1);
  col[d * CAP + pos] = s;
}

// ---------- W2 transpose to fp16 [n][k] (B^T fragment layout) ----------

__global__ __launch_bounds__(256) void k_w2t(const float* __restrict__ W2,
                                             _Float16* __restrict__ W2t) {
  const int t = blockIdx.x * 256 + threadIdx.x;  // 32768 total
  const int n = t >> 8;        // 0..127
  const int k = t & 255;       // 0..255
  W2t[n * 256 + k] = (_Float16)W2[k * F2 + n];
}

// ---------- fused: agg1 -> h1 = relu(.) fp16 -> t2h = fp16(dinv*(h1 W2)) ----

__global__ __launch_bounds__(256) void k_gemm12(
    const float* __restrict__ x, const int* __restrict__ cursor,
    const int* __restrict__ col, const float* __restrict__ W1,
    const float* __restrict__ b1, const _Float16* __restrict__ W2t,
    _Float16* __restrict__ t2h) {
  __shared__ float alds[MB * F0];                       // 640 B
  __shared__ float din[MB];                             // 64 B
  __shared__ __align__(16) _Float16 h1h[MB * H1S];      // 8.25 KB
  __shared__ __align__(16) _Float16 w2t[F2 * W2S];      // 18 KB
  __shared__ int   es[MB][EMAX];                        // 3 KB
  __shared__ float ew[MB][EMAX];                        // 3 KB
  const int tid = threadIdx.x;
  const int n0 = blockIdx.x * MB;
  // W2t chunk-0 prefetch FIRST: in flight under all of stage 0.
  // uint4 index map: u in {tid, tid+256, tid+512, tid+768}:
  //   n = u>>3, koff16B = u&7 ; global uint4 idx = n*32 + kc*8 + (u&7)
  const uint4* W2t4 = (const uint4*)W2t;
  const int gb = ((tid >> 3) << 5) + (tid & 7);
  uint4 pf0 = W2t4[gb];
  uint4 pf1 = W2t4[gb + 1024];
  uint4 pf2 = W2t4[gb + 2048];
  uint4 pf3 = W2t4[gb + 3072];
  // stage 0a: cooperative edge staging — 16 threads per node, one edge each.
  {
    const int m = tid >> 4;
    const int j0 = tid & 15;
    const int n = n0 + m;
    const int degraw = cursor[n];
    const int deg = min(degraw, EMAX);
    const int base = n * CAP;
    if (j0 == 0) din[m] = rsqrtf((float)(degraw + 1));
    for (int j = j0; j < deg; j += 16) {
      const int s = col[base + j];
      es[m][j] = s;
      ew[m][j] = rsqrtf((float)(cursor[s] + 1));
    }
  }
  __syncthreads();
  // stage 0b: x-gathers with LDS-sourced addresses (independent, pipelined)
  {
    const int m = tid >> 4;
    const int f = tid & 15;
    if (f < F0) {
      const int n = n0 + m;
      const int deg = min(cursor[n], EMAX);
      const float di = din[m];
      float acc = x[n * F0 + f] * di;  // self-loop
      int j = 0;
      for (; j + 3 < deg; j += 4) {
        const int s0 = es[m][j],     s1 = es[m][j + 1];
        const int s2 = es[m][j + 2], s3 = es[m][j + 3];
        const float q0 = ew[m][j],     q1 = ew[m][j + 1];
        const float q2 = ew[m][j + 2], q3 = ew[m][j + 3];
        acc += x[s0 * F0 + f] * q0 + x[s1 * F0 + f] * q1 +
               x[s2 * F0 + f] * q2 + x[s3 * F0 + f] * q3;
      }
      for (; j < deg; ++j) acc += x[es[m][j] * F0 + f] * ew[m][j];
      alds[m * F0 + f] = di * acc;
    }
  }
  __syncthreads();
  {  // phase A: thread = layer-1 channel c; writes h1h fp16 (k-contig per m)
    const int c = tid;
    float w1r[F0];
#pragma unroll
    for (int k = 0; k < F0; ++k) w1r[k] = W1[k * F1 + c];
    const float bb = b1[c];
#pragma unroll
    for (int m = 0; m < MB; ++m) {
      float acc = bb;
#pragma unroll
      for (int k = 0; k < F0; ++k) acc += alds[m * F0 + k] * w1r[k];
      h1h[m * H1S + c] = (_Float16)fmaxf(acc, 0.f);
    }
  }
  // phase B: MFMA. Wave wv owns 2 output tiles (16 nodes x 16 cols) at
  // n-offsets wv*32, wv*32+16. K=256 in 4 chunks of 64, reg-prefetch staging.
  const int lane = tid & 63;
  const int wv   = tid >> 6;
  const int lr   = lane & 15;
  const int lg   = lane >> 4;
  const int nt0  = wv * 32;
  f32x4 acc0 = {0.f, 0.f, 0.f, 0.f};
  f32x4 acc1 = {0.f, 0.f, 0.f, 0.f};
  // LDS store map for staged chunk: uint4 idx = (u>>3)*9 + (u&7)
  uint4* w2t4 = (uint4*)w2t;
  const int sb = (tid >> 3) * 9 + (tid & 7);
  for (int kc = 0; kc < F1 / BKC; ++kc) {
    __syncthreads();  // prev chunk consumed (kc=0: h1h written by phase A)
    w2t4[sb]       = pf0;
    w2t4[sb + 288] = pf1;
    w2t4[sb + 576] = pf2;
    w2t4[sb + 864] = pf3;
    __syncthreads();
    if (kc + 1 < F1 / BKC) {  // issue next-chunk loads
      const uint4* gnext = W2t4 + (kc + 1) * 8;
      pf0 = gnext[gb];
      pf1 = gnext[gb + 1024];
      pf2 = gnext[gb + 2048];
      pf3 = gnext[gb + 3072];
    }
#pragma unroll
    for (int ks = 0; ks < 2; ++ks) {
      const int kb = kc * BKC + ks * 32;         // global k base
      const f16x8 av = *(const f16x8*)&h1h[lr * H1S + kb + lg * 8];
      const f16x8 b0 = *(const f16x8*)&w2t[(nt0 + lr) * W2S + ks * 32 + lg * 8];
      const f16x8 b1v = *(const f16x8*)&w2t[(nt0 + 16 + lr) * W2S + ks * 32 + lg * 8];
      acc0 = __builtin_amdgcn_mfma_f32_16x16x32_f16(av, b0, acc0, 0, 0, 0);
      acc1 = __builtin_amdgcn_mfma_f32_16x16x32_f16(av, b1v, acc1, 0, 0, 0);
    }
  }
  // epilogue: C/D layout col=lane&15, row=(lane>>4)*4+reg; scale by din[row]
#pragma unroll
  for (int r = 0; r < 4; ++r) {
    const int row = lg * 4 + r;
    const float dn = din[row];
    t2h[(size_t)(n0 + row) * F2 + nt0 + lr]      = (_Float16)(acc0[r] * dn);
    t2h[(size_t)(n0 + row) * F2 + nt0 + 16 + lr] = (_Float16)(acc1[r] * dn);
  }
}

// ---------- layer-2 aggregation + layer-3 transform ----------
// 2 nodes per wave: half-wave (32 lanes) per node, 8 B/lane (4 fp16);
// 8 gathers in flight (deg~16 -> mostly 2 batches). fp16 rows = 256 B.

__device__ inline void acc_h4(uint2 u, float& a0, float& a1, float& a2, float& a3) {
  union { uint2 u; __half2 h[2]; } pk;
  pk.u = u;
  const float2 f0 = __half22float2(pk.h[0]);
  const float2 f1 = __half22float2(pk.h[1]);
  a0 += f0.x; a1 += f0.y; a2 += f1.x; a3 += f1.y;
}

__global__ __launch_bounds__(256) void k_agg2(
    const __half* __restrict__ t2h, const int* __restrict__ cursor,
    const int* __restrict__ col, const float* __restrict__ b2,
    const float* __restrict__ W3, float* __restrict__ t3s) {
  const int wave = (blockIdx.x * 256 + threadIdx.x) >> 6;
  const int lane = threadIdx.x & 63;
  const int half = lane >> 5;        // 0 or 1
  const int li   = lane & 31;
  const int n    = wave * 2 + half;  // 2500 blocks cover 20000 exactly
  if (n >= NN) return;
  const int deg = cursor[n];
  const int base = n * CAP;
  const int fx = li * 4;
  float a0 = 0.f, a1 = 0.f, a2 = 0.f, a3 = 0.f;
  acc_h4(*(const uint2*)&t2h[(size_t)n * F2 + fx], a0, a1, a2, a3);  // self
  int k = 0;
  for (; k + 7 < deg; k += 8) {  // 8 coalesced 256B gathers in flight
    const int s0 = col[base + k],     s1 = col[base + k + 1];
    const int s2 = col[base + k + 2], s3 = col[base + k + 3];
    const int s4 = col[base + k + 4], s5 = col[base + k + 5];
    const int s6 = col[base + k + 6], s7 = col[base + k + 7];
    const uint2 v0 = *(const uint2*)&t2h[(size_t)s0 * F2 + fx];
    const uint2 v1 = *(const uint2*)&t2h[(size_t)s1 * F2 + fx];
    const uint2 v2 = *(const uint2*)&t2h[(size_t)s2 * F2 + fx];
    const uint2 v3 = *(const uint2*)&t2h[(size_t)s3 * F2 + fx];
    const uint2 v4 = *(const uint2*)&t2h[(size_t)s4 * F2 + fx];
    const uint2 v5 = *(const uint2*)&t2h[(size_t)s5 * F2 + fx];
    const uint2 v6 = *(const uint2*)&t2h[(size_t)s6 * F2 + fx];
    const uint2 v7 = *(const uint2*)&t2h[(size_t)s7 * F2 + fx];
    acc_h4(v0, a0, a1, a2, a3); acc_h4(v1, a0, a1, a2, a3);
    acc_h4(v2, a0, a1, a2, a3); acc_h4(v3, a0, a1, a2, a3);
    acc_h4(v4, a0, a1, a2, a3); acc_h4(v5, a0, a1, a2, a3);
    acc_h4(v6, a0, a1, a2, a3); acc_h4(v7, a0, a1, a2, a3);
  }
  for (; k + 3 < deg; k += 4) {
    const int s0 = col[base + k],     s1 = col[base + k + 1];
    const int s2 = col[base + k + 2], s3 = col[base + k + 3];
    const uint2 v0 = *(const uint2*)&t2h[(size_t)s0 * F2 + fx];
    const uint2 v1 = *(const uint2*)&t2h[(size_t)s1 * F2 + fx];
    const uint2 v2 = *(const uint2*)&t2h[(size_t)s2 * F2 + fx];
    const uint2 v3 = *(const uint2*)&t2h[(size_t)s3 * F2 + fx];
    acc_h4(v0, a0, a1, a2, a3); acc_h4(v1, a0, a1, a2, a3);
    acc_h4(v2, a0, a1, a2, a3); acc_h4(v3, a0, a1, a2, a3);
  }
  for (; k < deg; ++k) {
    acc_h4(*(const uint2*)&t2h[(size_t)col[base + k] * F2 + fx], a0, a1, a2, a3);
  }
  const float di = rsqrtf((float)(deg + 1));
  const float4 bb = *(const float4*)&b2[fx];
  const float4 w3 = *(const float4*)&W3[fx];
  const float h0 = fmaxf(di * a0 + bb.x, 0.f);
  const float h1 = fmaxf(di * a1 + bb.y, 0.f);
  const float h2 = fmaxf(di * a2 + bb.z, 0.f);
  const float h3 = fmaxf(di * a3 + bb.w, 0.f);
  float p = (h0 * w3.x + h1 * w3.y) + (h2 * w3.z + h3 * w3.w);
#pragma unroll
  for (int off = 16; off > 0; off >>= 1) p += __shfl_down(p, off);  // within half
  if (li == 0) t3s[n] = di * p;
}

// ---------- layer-3 aggregation ----------
// 4 nodes per wave, 16 lanes per node -> coalesced col reads, 16-wide gathers.

__global__ __launch_bounds__(256) void k_agg3(
    const float* __restrict__ t3s, const int* __restrict__ cursor,
    const int* __restrict__ col, const float* __restrict__ b3,
    float* __restrict__ out) {
  const int wave = (blockIdx.x * 256 + threadIdx.x) >> 6;
  const int lane = threadIdx.x & 63;
  const int sub  = lane >> 4;       // 0..3
  const int li   = lane & 15;
  const int n    = wave * 4 + sub;  // 1250 blocks x 16 nodes cover 20000 exactly
  if (n >= NN) return;
  const int deg = cursor[n];
  const int base = n * CAP;
  float acc = 0.f;
  for (int j = li; j < deg; j += 16) acc += t3s[col[base + j]];
  acc += __shfl_xor(acc, 8);
  acc += __shfl_xor(acc, 4);
  acc += __shfl_xor(acc, 2);
  acc += __shfl_xor(acc, 1);
  if (li == 0)
    out[n] = rsqrtf((float)(deg + 1)) * (acc + t3s[n]) + b3[0];
}

extern "C" void kernel_launch(void* const* d_in, const int* in_sizes, int n_in,
                              void* d_out, int out_size, void* d_ws, size_t ws_size,
                              hipStream_t stream) {
  const float* x = (const float*)d_in[0];
  const int* ei = (const int*)d_in[1];
  const int* srcv = ei;       // edge_index[0]
  const int* dstv = ei + NE;  // edge_index[1]
  const float* W1 = (const float*)d_in[2];
  const float* b1 = (const float*)d_in[3];
  const float* W2 = (const float*)d_in[4];
  const float* b2 = (const float*)d_in[5];
  const float* W3 = (const float*)d_in[6];
  const float* b3 = (const float*)d_in[7];
  float* out = (float*)d_out;

  char* w = (char*)d_ws;
  auto alloc = [&](size_t bytes) -> void* {
    void* p = (void*)w;
    w += (bytes + 255) & ~(size_t)255;
    return p;
  };
  int*      cursor = (int*)     alloc(NN * 4);
  int*      col    = (int*)     alloc((size_t)NN * CAP * 4);
  _Float16* t2h    = (_Float16*)alloc((size_t)NN * F2 * 2);
  float*    t3s    = (float*)   alloc(NN * 4);
  _Float16* W2t    = (_Float16*)alloc((size_t)F2 * F1 * 2);

  (void)hipMemsetAsync(cursor, 0, NN * 4, stream);
  k_fill<<<(NE + 255) / 256, 256, 0, stream>>>(srcv, dstv, cursor, col);
  k_w2t<<<(F1 * F2) / 256, 256, 0, stream>>>(W2, W2t);
  k_gemm12<<<NN / MB, 256, 0, stream>>>(x, cursor, col, W1, b1, W2t, t2h);
  k_agg2<<<NN / 8, 256, 0, stream>>>((const __half*)t2h, cursor, col, b2, W3, t3s);
  k_agg3<<<(NN + 15) / 16, 256, 0, stream>>>(t3s, cursor, col, b3, out);
}